// Round 2
// baseline (3503.483 us; speedup 1.0000x reference)
//
#include <hip/hip_runtime.h>

#define NPTS 4096
#define CH 64
#define BATCH 8
#define KNN 20
#define NEG_SLOPE 0.2f
#define EPSV 1e-5f
#define NEG_INF (-3.4e38f)

// ---------------- K0: xx[b,n] = sum_c x[b,c,n]^2 ----------------
__global__ void k_xx(const float* __restrict__ x, float* __restrict__ xx) {
  int t = blockIdx.x * 256 + threadIdx.x;          // [0, B*N)
  int b = t >> 12, n = t & (NPTS - 1);
  const float* xp = x + ((size_t)b * CH * NPTS) + n;
  float s = 0.f;
#pragma unroll
  for (int c = 0; c < CH; ++c) { float v = xp[(size_t)c * NPTS]; s = fmaf(v, v, s); }
  xx[t] = s;
}

// ---------------- K2: P'[t,o], Q'[t,o] ----------------
__global__ void k_pq(const float* __restrict__ x, const float* __restrict__ W,
                     const float* __restrict__ gamma, const float* __restrict__ beta,
                     const float* __restrict__ rmean, const float* __restrict__ rvar,
                     float* __restrict__ P, float* __restrict__ Q) {
  __shared__ float Ws1[CH * CH];   // [c][o], W1*inv
  __shared__ float Wsd[CH * CH];   // [c][o], (W2-W1)*inv
  int tid = threadIdx.x;
  for (int i = tid; i < CH * CH; i += 256) {
    int o = i & 63, c = i >> 6;
    float s = gamma[o] * rsqrtf(rvar[o] + EPSV);
    float w1 = W[o * 128 + c], w2 = W[o * 128 + 64 + c];
    Ws1[c * 64 + o] = w1 * s;
    Wsd[c * 64 + o] = (w2 - w1) * s;
  }
  __syncthreads();
  int o = tid & 63, ng = tid >> 6;
  float s = gamma[o] * rsqrtf(rvar[o] + EPSV);
  float shift = beta[o] - rmean[o] * s;
  int base = blockIdx.x * 16;
  for (int rp = 0; rp < 4; ++rp) {
    int t = base + rp * 4 + ng;                    // row in [0, B*N)
    int b = t >> 12, n = t & (NPTS - 1);
    const float* xp = x + ((size_t)b * CH * NPTS) + n;
    float accp = 0.f, accq = 0.f;
#pragma unroll 8
    for (int c = 0; c < CH; ++c) {
      float xv = xp[(size_t)c * NPTS];
      accp = fmaf(xv, Ws1[c * 64 + o], accp);
      accq = fmaf(xv, Wsd[c * 64 + o], accq);
    }
    P[(size_t)t * 64 + o] = accp;
    Q[(size_t)t * 64 + o] = accq + shift;
  }
}

// ---------------- K1: fused distance-GEMM + top-20 selection ----------------
// Block: 256 threads. Tile: 64 rows (n) x 128 cols (m), 4x8 per thread.
// LDS: As 64c*64n (16KB) | Bs 64c*128m (32KB) | Ds 64*64 swizzled (16KB) = 64KB
__launch_bounds__(256, 2)
__global__ void k_knn(const float* __restrict__ x, const float* __restrict__ xx,
                      int* __restrict__ idxout) {
  __shared__ float S[16384];
  float* As = S;             // [c*64 + n]
  float* Bs = S + 4096;      // [c*128 + m]
  float* Ds = S + 12288;     // swizzled [r*64 + ((col+r)&63)]
  int tid = threadIdx.x;
  int nb = blockIdx.x, b = blockIdx.y;
  int n0 = nb * 64;
  const float* xb = x + (size_t)b * CH * NPTS;
  const float* xxb = xx + b * NPTS;

  // stage A-tile once
#pragma unroll
  for (int k = 0; k < 4; ++k) {
    int chunk = tid + 256 * k;                     // 0..1023
    int c = chunk >> 4, cn = (chunk & 15) << 2;
    float4 v = *(const float4*)(xb + (size_t)c * NPTS + n0 + cn);
    *(float4*)(As + c * 64 + cn) = v;
  }

  int tn = tid & 15, tm = tid >> 4;                // GEMM: rows 4tn.., cols 8tm..
  int selr = tid & 63, selq = tid >> 6;            // selection: row, quarter

  float xnr[4];
#pragma unroll
  for (int i = 0; i < 4; ++i) xnr[i] = xxb[n0 + 4 * tn + i];

  float tv[KNN]; int ti[KNN];
#pragma unroll
  for (int j = 0; j < KNN; ++j) { tv[j] = NEG_INF; ti[j] = 0; }

  for (int mt = 0; mt < NPTS / 128; ++mt) {
    int m0 = mt * 128;
    __syncthreads();                               // prior scans done
    // stage B-tile
#pragma unroll
    for (int k = 0; k < 8; ++k) {
      int chunk = tid + 256 * k;                   // 0..2047
      int c = chunk >> 5, cm = (chunk & 31) << 2;
      float4 v = *(const float4*)(xb + (size_t)c * NPTS + m0 + cm);
      *(float4*)(Bs + c * 128 + cm) = v;
    }
    __syncthreads();

    float acc[4][8];
#pragma unroll
    for (int i = 0; i < 4; ++i)
#pragma unroll
      for (int j = 0; j < 8; ++j) acc[i][j] = 0.f;

#pragma unroll 4
    for (int c = 0; c < CH; ++c) {
      float4 a  = *(const float4*)(As + c * 64 + 4 * tn);
      float4 b0 = *(const float4*)(Bs + c * 128 + 8 * tm);
      float4 b1 = *(const float4*)(Bs + c * 128 + 8 * tm + 4);
      float av[4] = {a.x, a.y, a.z, a.w};
      float bv[8] = {b0.x, b0.y, b0.z, b0.w, b1.x, b1.y, b1.z, b1.w};
#pragma unroll
      for (int i = 0; i < 4; ++i)
#pragma unroll
        for (int j = 0; j < 8; ++j) acc[i][j] = fmaf(av[i], bv[j], acc[i][j]);
    }

    float xmv[8];
#pragma unroll
    for (int j = 0; j < 8; ++j) xmv[j] = xxb[m0 + 8 * tm + j];

    for (int h = 0; h < 2; ++h) {
      __syncthreads();                             // previous half's scan done
      if ((tm >> 3) == h) {
        int tml = tm & 7;
#pragma unroll
        for (int i = 0; i < 4; ++i) {
          int r = 4 * tn + i;
#pragma unroll
          for (int jj = 0; jj < 8; ++jj) {
            int j2 = (jj + tn) & 7;                // rotate to spread banks
            int cl = 8 * tml + j2;                 // local col within half
            // d = (2*G - xx_n) - xx_m  (2*G exact -> matches ref op order)
            float d = (2.f * acc[i][j2] - xnr[i]) - xmv[j2];
            Ds[r * 64 + ((cl + r) & 63)] = d;
          }
        }
      }
      __syncthreads();
      int cbase = 16 * selq;
      for (int jj = 0; jj < 16; ++jj) {
        int cl = cbase + jj;
        float d = Ds[selr * 64 + ((cl + selr) & 63)];
        int m = m0 + 64 * h + cl;
        if (d > tv[KNN - 1]) {
          float cv = d; int ci = m;
#pragma unroll
          for (int s = 0; s < KNN; ++s) {
            if (tv[s] < cv) {
              float t1 = tv[s]; tv[s] = cv; cv = t1;
              int t2 = ti[s]; ti[s] = ci; ci = t2;
            }
          }
        }
      }
    }
  }

  // ---- merge 4 sorted lists per row -> global top-20 ----
  __syncthreads();
  float* MV = S;                                   // 64*4*20 = 5120 floats
  int* MI = (int*)(S + 5120);                      // 5120 ints
#pragma unroll
  for (int j = 0; j < KNN; ++j) {
    MV[(selr * 4 + selq) * KNN + j] = tv[j];
    MI[(selr * 4 + selq) * KNN + j] = ti[j];
  }
  __syncthreads();
  if (tid < 64) {
    int r = tid;
    int p0 = 0, p1 = 0, p2 = 0, p3 = 0;
    int* op = idxout + (size_t)(b * NPTS + n0 + r) * KNN;
    for (int kk = 0; kk < KNN; ++kk) {
      float v0 = (p0 < KNN) ? MV[(r * 4 + 0) * KNN + p0] : NEG_INF;
      float v1 = (p1 < KNN) ? MV[(r * 4 + 1) * KNN + p1] : NEG_INF;
      float v2 = (p2 < KNN) ? MV[(r * 4 + 2) * KNN + p2] : NEG_INF;
      float v3 = (p3 < KNN) ? MV[(r * 4 + 3) * KNN + p3] : NEG_INF;
      int i0 = (p0 < KNN) ? MI[(r * 4 + 0) * KNN + p0] : 0x7fffffff;
      int i1 = (p1 < KNN) ? MI[(r * 4 + 1) * KNN + p1] : 0x7fffffff;
      int i2 = (p2 < KNN) ? MI[(r * 4 + 2) * KNN + p2] : 0x7fffffff;
      int i3 = (p3 < KNN) ? MI[(r * 4 + 3) * KNN + p3] : 0x7fffffff;
      float bvv = v0; int bi = i0; int bq = 0;
      if (v1 > bvv || (v1 == bvv && i1 < bi)) { bvv = v1; bi = i1; bq = 1; }
      if (v2 > bvv || (v2 == bvv && i2 < bi)) { bvv = v2; bi = i2; bq = 2; }
      if (v3 > bvv || (v3 == bvv && i3 < bi)) { bvv = v3; bi = i3; bq = 3; }
      op[kk] = bi;
      if (bq == 0) ++p0; else if (bq == 1) ++p1; else if (bq == 2) ++p2; else ++p3;
    }
  }
}

// ---------------- K3: gather + max + leaky, transpose to (B,O,N) ----------------
__global__ void k_out(const float* __restrict__ P, const float* __restrict__ Q,
                      const int* __restrict__ idx, float* __restrict__ out) {
  __shared__ float T[64 * 65];
  int tid = threadIdx.x;
  int nb = blockIdx.x, b = blockIdx.y;
  int n0 = nb * 64;
  int o = tid & 63, ng = tid >> 6;
  const float* Pb = P + (size_t)b * NPTS * 64;
  for (int p = 0; p < 16; ++p) {
    int nl = p * 4 + ng;
    int n = n0 + nl;
    const int* ip = idx + (size_t)(b * NPTS + n) * KNN;
    float mx = NEG_INF;
#pragma unroll
    for (int k = 0; k < KNN; ++k) {
      int id = ip[k];
      float v = Pb[(size_t)id * 64 + o];
      mx = fmaxf(mx, v);
    }
    float z = mx + Q[(size_t)(b * NPTS + n) * 64 + o];
    z = (z >= 0.f) ? z : NEG_SLOPE * z;
    T[o * 65 + nl] = z;
  }
  __syncthreads();
  float* ob = out + (size_t)b * 64 * NPTS + n0;
  int nl = tid & 63;
  for (int w = 0; w < 16; ++w) {
    int oo = w * 4 + ng;
    ob[(size_t)oo * NPTS + nl] = T[oo * 65 + nl];
  }
}

extern "C" void kernel_launch(void* const* d_in, const int* in_sizes, int n_in,
                              void* d_out, int out_size, void* d_ws, size_t ws_size,
                              hipStream_t stream) {
  const float* x     = (const float*)d_in[0];
  const float* W     = (const float*)d_in[1];
  const float* gamma = (const float*)d_in[2];
  const float* beta  = (const float*)d_in[3];
  const float* rmean = (const float*)d_in[4];
  const float* rvar  = (const float*)d_in[5];
  float* out = (float*)d_out;

  float* xx = (float*)d_ws;                        // 32768 floats
  float* P  = xx + 32768;                          // 2097152 floats
  float* Q  = P + 2097152;                         // 2097152 floats
  int*   idx = (int*)(Q + 2097152);                // 655360 ints

  k_xx<<<BATCH * NPTS / 256, 256, 0, stream>>>(x, xx);
  k_pq<<<BATCH * NPTS / 16, 256, 0, stream>>>(x, W, gamma, beta, rmean, rvar, P, Q);
  k_knn<<<dim3(NPTS / 64, BATCH), 256, 0, stream>>>(x, xx, idx);
  k_out<<<dim3(NPTS / 64, BATCH), 256, 0, stream>>>(P, Q, idx, out);
}

// Round 3
// 723.951 us; speedup vs baseline: 4.8394x; 4.8394x over previous
//
#include <hip/hip_runtime.h>

#define NPTS 4096
#define CH 64
#define BATCH 8
#define KNN 20
#define NEG_SLOPE 0.2f
#define EPSV 1e-5f
#define NEG_INF (-3.4e38f)

// ---------------- K0: xx[b,n] = sum_c x[b,c,n]^2 ----------------
__global__ void k_xx(const float* __restrict__ x, float* __restrict__ xx) {
  int t = blockIdx.x * 256 + threadIdx.x;          // [0, B*N)
  int b = t >> 12, n = t & (NPTS - 1);
  const float* xp = x + ((size_t)b * CH * NPTS) + n;
  float s = 0.f;
#pragma unroll
  for (int c = 0; c < CH; ++c) { float v = xp[(size_t)c * NPTS]; s = fmaf(v, v, s); }
  xx[t] = s;
}

// ---------------- K2: P'[t,o], Q'[t,o] ----------------
__global__ void k_pq(const float* __restrict__ x, const float* __restrict__ W,
                     const float* __restrict__ gamma, const float* __restrict__ beta,
                     const float* __restrict__ rmean, const float* __restrict__ rvar,
                     float* __restrict__ P, float* __restrict__ Q) {
  __shared__ float Ws1[CH * CH];   // [c][o], W1*inv
  __shared__ float Wsd[CH * CH];   // [c][o], (W2-W1)*inv
  int tid = threadIdx.x;
  for (int i = tid; i < CH * CH; i += 256) {
    int o = i & 63, c = i >> 6;
    float s = gamma[o] * rsqrtf(rvar[o] + EPSV);
    float w1 = W[o * 128 + c], w2 = W[o * 128 + 64 + c];
    Ws1[c * 64 + o] = w1 * s;
    Wsd[c * 64 + o] = (w2 - w1) * s;
  }
  __syncthreads();
  int o = tid & 63, ng = tid >> 6;
  float s = gamma[o] * rsqrtf(rvar[o] + EPSV);
  float shift = beta[o] - rmean[o] * s;
  int base = blockIdx.x * 16;
  for (int rp = 0; rp < 4; ++rp) {
    int t = base + rp * 4 + ng;                    // row in [0, B*N)
    int b = t >> 12, n = t & (NPTS - 1);
    const float* xp = x + ((size_t)b * CH * NPTS) + n;
    float accp = 0.f, accq = 0.f;
#pragma unroll 8
    for (int c = 0; c < CH; ++c) {
      float xv = xp[(size_t)c * NPTS];
      accp = fmaf(xv, Ws1[c * 64 + o], accp);
      accq = fmaf(xv, Wsd[c * 64 + o], accq);
    }
    P[(size_t)t * 64 + o] = accp;
    Q[(size_t)t * 64 + o] = accq + shift;
  }
}

// ---------------- K1: fused distance-GEMM + wave-distributed top-20 ----------
// Block: 256 threads. Tile: 64 rows (n) x 128 cols (m), 4x8 per thread.
// LDS: As 64c*64n (16KB) + [Bs 64c*128m (32KB) OVERLAID with Ds 64r*132 (33KB)]
//      = 49KB -> 3 blocks/CU.
// Selection: wave w owns rows 16w..16w+15. Top list for row r is DISTRIBUTED:
// lane l holds the (l+1)-th best (value,index), sorted desc across lanes
// (effectively top-64; we emit lanes 0..19). Insert = ballot-gated parallel
// shift (no serial 20-deep insertion sort, no dynamic register indexing).
__launch_bounds__(256, 3)
__global__ void k_knn(const float* __restrict__ x, const float* __restrict__ xx,
                      int* __restrict__ idxout) {
  __shared__ float S[12544];
  float* As = S;                 // [c*64 + n]
  float* Bs = S + 4096;         // [c*128 + m]   (dead once GEMM of tile done)
  float* Ds = S + 4096;         // [r*132 + col] (overlaid on Bs)
  int tid = threadIdx.x;
  int nb = blockIdx.x, b = blockIdx.y;
  int n0 = nb * 64;
  const float* xb = x + (size_t)b * CH * NPTS;
  const float* xxb = xx + b * NPTS;
  int lane = tid & 63;
  int w = tid >> 6;

  // stage A-tile once
#pragma unroll
  for (int k = 0; k < 4; ++k) {
    int chunk = tid + 256 * k;                     // 0..1023
    int c = chunk >> 4, cn = (chunk & 15) << 2;
    float4 v = *(const float4*)(xb + (size_t)c * NPTS + n0 + cn);
    *(float4*)(As + c * 64 + cn) = v;
  }

  int tn = tid & 15, tm = tid >> 4;                // GEMM: rows 4tn.., cols 8tm..

  float xnr[4];
#pragma unroll
  for (int i = 0; i < 4; ++i) xnr[i] = xxb[n0 + 4 * tn + i];

  // distributed top lists: lane l holds l-th best of rows 16w+0..15
  float val[16]; int idx[16];
#pragma unroll
  for (int r = 0; r < 16; ++r) { val[r] = NEG_INF; idx[r] = 0; }

  for (int mt = 0; mt < NPTS / 128; ++mt) {
    int m0 = mt * 128;
    __syncthreads();                               // prev tile's Ds reads done
    // stage B-tile (overwrites Ds region)
#pragma unroll
    for (int k = 0; k < 8; ++k) {
      int chunk = tid + 256 * k;                   // 0..2047
      int c = chunk >> 5, cm = (chunk & 31) << 2;
      float4 v = *(const float4*)(xb + (size_t)c * NPTS + m0 + cm);
      *(float4*)(Bs + c * 128 + cm) = v;
    }
    __syncthreads();

    float acc[4][8];
#pragma unroll
    for (int i = 0; i < 4; ++i)
#pragma unroll
      for (int j = 0; j < 8; ++j) acc[i][j] = 0.f;

#pragma unroll 4
    for (int c = 0; c < CH; ++c) {                 // SAME fp op order as R2 (bitexact d)
      float4 a  = *(const float4*)(As + c * 64 + 4 * tn);
      float4 b0 = *(const float4*)(Bs + c * 128 + 8 * tm);
      float4 b1 = *(const float4*)(Bs + c * 128 + 8 * tm + 4);
      float av[4] = {a.x, a.y, a.z, a.w};
      float bv[8] = {b0.x, b0.y, b0.z, b0.w, b1.x, b1.y, b1.z, b1.w};
#pragma unroll
      for (int i = 0; i < 4; ++i)
#pragma unroll
        for (int j = 0; j < 8; ++j) acc[i][j] = fmaf(av[i], bv[j], acc[i][j]);
    }

    float xmv[8];
#pragma unroll
    for (int j = 0; j < 8; ++j) xmv[j] = xxb[m0 + 8 * tm + j];

    __syncthreads();                               // GEMM's Bs reads done; Ds may overwrite
    // write distances to Ds with STATIC register indices, float4 stores.
#pragma unroll
    for (int i = 0; i < 4; ++i) {
      int R = 4 * tn + i;
      float4 d0, d1;
      d0.x = (2.f * acc[i][0] - xnr[i]) - xmv[0];
      d0.y = (2.f * acc[i][1] - xnr[i]) - xmv[1];
      d0.z = (2.f * acc[i][2] - xnr[i]) - xmv[2];
      d0.w = (2.f * acc[i][3] - xnr[i]) - xmv[3];
      d1.x = (2.f * acc[i][4] - xnr[i]) - xmv[4];
      d1.y = (2.f * acc[i][5] - xnr[i]) - xmv[5];
      d1.z = (2.f * acc[i][6] - xnr[i]) - xmv[6];
      d1.w = (2.f * acc[i][7] - xnr[i]) - xmv[7];
      *(float4*)(Ds + R * 132 + 8 * tm)     = d0;
      *(float4*)(Ds + R * 132 + 8 * tm + 4) = d1;
    }
    __syncthreads();

    // selection: wave w scans rows 16w..16w+15, 2 groups of 64 cols (lane=col)
#pragma unroll
    for (int r = 0; r < 16; ++r) {
      int R = 16 * w + r;
      const float* drow = Ds + R * 132;
#pragma unroll
      for (int g = 0; g < 2; ++g) {
        float d = drow[64 * g + lane];
        float th = __shfl(val[r], KNN - 1);        // current 20th-best
        unsigned long long hit = __ballot(d > th); // strict > : exact lax.top_k ties
        int mg = m0 + 64 * g;
        while (hit) {
          int j = __builtin_ctzll(hit);            // lowest column first (stable)
          hit &= hit - 1;
          float cv = __shfl(d, j);
          int cm = mg + j;
          unsigned long long km = __ballot(val[r] >= cv);  // existing equals stay above
          int cnt = __popcll(km);                  // insert position (keep is a prefix)
          float sv = __shfl_up(val[r], 1);
          int si = __shfl_up(idx[r], 1);
          if (lane >= cnt) {
            val[r] = (lane == cnt) ? cv : sv;
            idx[r] = (lane == cnt) ? cm : si;
          }
        }
      }
    }
  }

  // emit: lane l (<20) holds l-th best index for row 16w+r
#pragma unroll
  for (int r = 0; r < 16; ++r) {
    int n = n0 + 16 * w + r;
    if (lane < KNN) idxout[(size_t)(b * NPTS + n) * KNN + lane] = idx[r];
  }
}

// ---------------- K3: gather + max + leaky, transpose to (B,O,N) ----------------
__global__ void k_out(const float* __restrict__ P, const float* __restrict__ Q,
                      const int* __restrict__ idx, float* __restrict__ out) {
  __shared__ float T[64 * 65];
  int tid = threadIdx.x;
  int nb = blockIdx.x, b = blockIdx.y;
  int n0 = nb * 64;
  int o = tid & 63, ng = tid >> 6;
  const float* Pb = P + (size_t)b * NPTS * 64;
  for (int p = 0; p < 16; ++p) {
    int nl = p * 4 + ng;
    int n = n0 + nl;
    const int* ip = idx + (size_t)(b * NPTS + n) * KNN;
    float mx = NEG_INF;
#pragma unroll
    for (int k = 0; k < KNN; ++k) {
      int id = ip[k];
      float v = Pb[(size_t)id * 64 + o];
      mx = fmaxf(mx, v);
    }
    float z = mx + Q[(size_t)(b * NPTS + n) * 64 + o];
    z = (z >= 0.f) ? z : NEG_SLOPE * z;
    T[o * 65 + nl] = z;
  }
  __syncthreads();
  float* ob = out + (size_t)b * 64 * NPTS + n0;
  int nl = tid & 63;
  for (int w = 0; w < 16; ++w) {
    int oo = w * 4 + ng;
    ob[(size_t)oo * NPTS + nl] = T[oo * 65 + nl];
  }
}

extern "C" void kernel_launch(void* const* d_in, const int* in_sizes, int n_in,
                              void* d_out, int out_size, void* d_ws, size_t ws_size,
                              hipStream_t stream) {
  const float* x     = (const float*)d_in[0];
  const float* W     = (const float*)d_in[1];
  const float* gamma = (const float*)d_in[2];
  const float* beta  = (const float*)d_in[3];
  const float* rmean = (const float*)d_in[4];
  const float* rvar  = (const float*)d_in[5];
  float* out = (float*)d_out;

  float* xx = (float*)d_ws;                        // 32768 floats
  float* P  = xx + 32768;                          // 2097152 floats
  float* Q  = P + 2097152;                         // 2097152 floats
  int*   idx = (int*)(Q + 2097152);                // 655360 ints

  k_xx<<<BATCH * NPTS / 256, 256, 0, stream>>>(x, xx);
  k_pq<<<BATCH * NPTS / 16, 256, 0, stream>>>(x, W, gamma, beta, rmean, rvar, P, Q);
  k_knn<<<dim3(NPTS / 64, BATCH), 256, 0, stream>>>(x, xx, idx);
  k_out<<<dim3(NPTS / 64, BATCH), 256, 0, stream>>>(P, Q, idx, out);
}